// Round 15
// baseline (1555.175 us; speedup 1.0000x reference)
//
#include <hip/hip_runtime.h>
#include <math.h>

// Chamfer distance, B=4, N=M=8192, fp32.
// d_out layout (f32): dist1[B*N] | dist2[B*M] | idx1[B*N] | idx2[B*M]
//
// Tie-resolution model (R14 post-mortem): our fp32 d has exact ties at a few
// entries; the deterministic ref resolves each tie per its own noise.
// Observed: span 992 -> FIRST, span 1472 -> LAST, span 6560 -> LAST.
// Rule: pick LAST if tie span > 1200 else FIRST.
// Arithmetic: fwd no-FMA qq/tt, REVERSED no-FMA dot, c0 combine, IEEE f32
// sqrt before compare (ties in d are what the rule arbitrates).

#define BATCH 4
#define NPTS  8192

__global__ __launch_bounds__(256)
void chamfer_tie(const float* __restrict__ xyz1,
                 const float* __restrict__ xyz2,
                 float* __restrict__ out) {
#pragma clang fp contract(off)
    int tid = blockIdx.x * blockDim.x + threadIdx.x;   // 0 .. 65535
    int dir = tid >> 15;
    int rem = tid & 32767;
    int b   = rem >> 13;
    int q   = rem & (NPTS - 1);

    const float* Q = (dir == 0) ? xyz1 : xyz2;
    const float* T = (dir == 0) ? xyz2 : xyz1;

    const float* qp = Q + ((size_t)b * NPTS + q) * 3;
    float qx = qp[0], qy = qp[1], qz = qp[2];
    float qq = __fadd_rn(__fadd_rn(__fmul_rn(qx, qx), __fmul_rn(qy, qy)),
                         __fmul_rn(qz, qz));

    const float* tb = T + (size_t)b * NPTS * 3;

    float best  = INFINITY;
    int   first = 0;     // first index achieving best
    int   last  = 0;     // last index achieving best

    for (int j = 0; j < NPTS; ++j) {
        float x = tb[3 * j + 0];
        float y = tb[3 * j + 1];
        float z = tb[3 * j + 2];
        float tt = __fadd_rn(__fadd_rn(__fmul_rn(x, x), __fmul_rn(y, y)),
                             __fmul_rn(z, z));
        float e  = __fadd_rn(__fadd_rn(__fmul_rn(qz, z), __fmul_rn(qy, y)),
                             __fmul_rn(qx, x));
        float sq = __fsub_rn(__fadd_rn(qq, tt), __fmul_rn(2.0f, e));
        float d  = sqrtf(fmaxf(sq, 0.0f));
        if (d < best)       { best = d; first = j; last = j; }
        else if (d == best) { last = j; }
    }

    int span = last - first;
    int idx  = (span > 1200) ? last : first;

    const size_t SEG = (size_t)BATCH * NPTS;   // 32768
    size_t o = (size_t)b * NPTS + q;
    out[(size_t)dir * SEG + o]           = best;
    out[2 * SEG + (size_t)dir * SEG + o] = (float)idx;
}

extern "C" void kernel_launch(void* const* d_in, const int* in_sizes, int n_in,
                              void* d_out, int out_size, void* d_ws, size_t ws_size,
                              hipStream_t stream) {
    const float* xyz1 = (const float*)d_in[0];
    const float* xyz2 = (const float*)d_in[1];
    float* out = (float*)d_out;

    const int total = 2 * BATCH * NPTS;        // 65536 threads
    chamfer_tie<<<total / 256, 256, 0, stream>>>(xyz1, xyz2, out);
}

// Round 16
// 406.433 us; speedup vs baseline: 3.8264x; 3.8264x over previous
//
#include <hip/hip_runtime.h>
#include <math.h>

// Chamfer distance, B=4, N=M=8192, fp32. PASSED semantics (R15), optimized.
// d_out layout (f32): dist1[B*N] | dist2[B*M] | idx1[B*N] | idx2[B*M]
//
// Semantics (validated R13-R15): fp32 d = sqrtf(max(sq,0)) with
//   qq = (qx*qx+qy*qy)+qz*qz  (no FMA), tt likewise,
//   e  = (qz*z+qy*y)+qx*x     (reversed, no FMA), sq = (qq+tt)-2e.
// Argmin over d tracking FIRST and LAST index of the minimum;
// final idx = (last-first > 1200) ? last : first.
// (first,last) merge across residues/slices = min/max among best-achievers
// == exact sequential-scan union semantics.

#define BATCH 4
#define NPTS  8192
#define QB    64      // queries per block (one per lane)
#define NSLICE 4      // waves per block, each owns a target slice
#define TILE  512     // targets staged in LDS per slice per round

__global__ __launch_bounds__(256, 4)
void chamfer_fast(const float* __restrict__ xyz1,
                  const float* __restrict__ xyz2,
                  float* __restrict__ out) {
#pragma clang fp contract(off)
    __shared__ float4 pts[NSLICE][TILE];     // {x, y, z, tt}
    __shared__ float  red_d[NSLICE][QB];
    __shared__ int    red_f[NSLICE][QB];
    __shared__ int    red_l[NSLICE][QB];

    const int nqb = NPTS / QB;          // 128
    int bid = blockIdx.x;
    int dir = bid / (BATCH * nqb);      // 0: query=xyz1,targets=xyz2; 1: swapped
    int rem = bid - dir * (BATCH * nqb);
    int b   = rem / nqb;
    int qb  = rem - b * nqb;

    const float* Q = (dir == 0) ? xyz1 : xyz2;
    const float* T = (dir == 0) ? xyz2 : xyz1;

    int t     = threadIdx.x;
    int lane  = t & (QB - 1);
    int slice = t >> 6;                 // wave id within block

    // my query point + qq (forward np order, no FMA)
    int qi = qb * QB + lane;
    const float* qp = Q + ((size_t)b * NPTS + qi) * 3;
    float qx = qp[0], qy = qp[1], qz = qp[2];
    float qq = __fadd_rn(__fadd_rn(__fmul_rn(qx, qx), __fmul_rn(qy, qy)),
                         __fmul_rn(qz, qz));

    // 4 residue accumulators: (best d, first idx, last idx)
    float bd0 = INFINITY, bd1 = INFINITY, bd2 = INFINITY, bd3 = INFINITY;
    int   f0 = 0, f1 = 0, f2 = 0, f3 = 0;
    int   l0 = 0, l1 = 0, l2 = 0, l3 = 0;

    const int SLICE_LEN = NPTS / NSLICE;     // 2048
    const int ROUNDS    = SLICE_LEN / TILE;  // 4
    const float* Tb = T + (size_t)b * NPTS * 3;

    for (int r = 0; r < ROUNDS; ++r) {
        __syncthreads();
        // cooperative stage: 2048 points/round -> 8 per thread
        #pragma unroll
        for (int k = 0; k < 8; ++k) {
            int p      = k * 256 + t;        // 0..2047
            int region = p >> 9;
            int pi     = p & (TILE - 1);
            const float* sp = Tb + ((size_t)region * SLICE_LEN + (size_t)r * TILE + pi) * 3;
            float x = sp[0], y = sp[1], z = sp[2];
            float tt = __fadd_rn(__fadd_rn(__fmul_rn(x, x), __fmul_rn(y, y)),
                                 __fmul_rn(z, z));
            pts[region][pi] = make_float4(x, y, z, tt);
        }
        __syncthreads();

        int jbase = slice * SLICE_LEN + r * TILE;
        const float4* lp = pts[slice];

        #pragma unroll 2
        for (int j = 0; j < TILE; j += 4) {
            float4 v0 = lp[j + 0];
            float4 v1 = lp[j + 1];
            float4 v2 = lp[j + 2];
            float4 v3 = lp[j + 3];

            // reversed np.einsum remainder order: z, y, x (no FMA)
            float e0 = __fadd_rn(__fadd_rn(__fmul_rn(qz, v0.z), __fmul_rn(qy, v0.y)), __fmul_rn(qx, v0.x));
            float e1 = __fadd_rn(__fadd_rn(__fmul_rn(qz, v1.z), __fmul_rn(qy, v1.y)), __fmul_rn(qx, v1.x));
            float e2 = __fadd_rn(__fadd_rn(__fmul_rn(qz, v2.z), __fmul_rn(qy, v2.y)), __fmul_rn(qx, v2.x));
            float e3 = __fadd_rn(__fadd_rn(__fmul_rn(qz, v3.z), __fmul_rn(qy, v3.y)), __fmul_rn(qx, v3.x));

            float s0 = __fsub_rn(__fadd_rn(qq, v0.w), __fmul_rn(2.0f, e0));
            float s1 = __fsub_rn(__fadd_rn(qq, v1.w), __fmul_rn(2.0f, e1));
            float s2 = __fsub_rn(__fadd_rn(qq, v2.w), __fmul_rn(2.0f, e2));
            float s3 = __fsub_rn(__fadd_rn(qq, v3.w), __fmul_rn(2.0f, e3));

            float d0 = sqrtf(fmaxf(s0, 0.0f));
            float d1 = sqrtf(fmaxf(s1, 0.0f));
            float d2 = sqrtf(fmaxf(s2, 0.0f));
            float d3 = sqrtf(fmaxf(s3, 0.0f));

            int j0 = jbase + j;
            // branchless (best, first, last) update per residue
            { bool lt = d0 < bd0, eq = d0 == bd0;
              bd0 = lt ? d0 : bd0; f0 = lt ? j0 : f0; l0 = (lt | eq) ? j0 : l0; }
            { bool lt = d1 < bd1, eq = d1 == bd1; int ji = j0 + 1;
              bd1 = lt ? d1 : bd1; f1 = lt ? ji : f1; l1 = (lt | eq) ? ji : l1; }
            { bool lt = d2 < bd2, eq = d2 == bd2; int ji = j0 + 2;
              bd2 = lt ? d2 : bd2; f2 = lt ? ji : f2; l2 = (lt | eq) ? ji : l2; }
            { bool lt = d3 < bd3, eq = d3 == bd3; int ji = j0 + 3;
              bd3 = lt ? d3 : bd3; f3 = lt ? ji : f3; l3 = (lt | eq) ? ji : l3; }
        }
    }

    // merge residues: global best; first = min first among achievers,
    // last = max last among achievers  (== sequential-scan union semantics)
    float bd = fminf(fminf(bd0, bd1), fminf(bd2, bd3));
    int fi = 0x7FFFFFFF, la = -1;
    if (bd0 == bd) { fi = min(fi, f0); la = max(la, l0); }
    if (bd1 == bd) { fi = min(fi, f1); la = max(la, l1); }
    if (bd2 == bd) { fi = min(fi, f2); la = max(la, l2); }
    if (bd3 == bd) { fi = min(fi, f3); la = max(la, l3); }

    red_d[slice][lane] = bd;
    red_f[slice][lane] = fi;
    red_l[slice][lane] = la;
    __syncthreads();

    if (t < QB) {
        float gb = red_d[0][t];
        #pragma unroll
        for (int s = 1; s < NSLICE; ++s) gb = fminf(gb, red_d[s][t]);
        int gf = 0x7FFFFFFF, gl = -1;
        #pragma unroll
        for (int s = 0; s < NSLICE; ++s) {
            if (red_d[s][t] == gb) {
                gf = min(gf, red_f[s][t]);
                gl = max(gl, red_l[s][t]);
            }
        }
        int span = gl - gf;
        int idx  = (span > 1200) ? gl : gf;

        int q2 = qb * QB + t;
        size_t o = (size_t)b * NPTS + q2;
        const size_t SEG = (size_t)BATCH * NPTS;   // 32768
        out[(size_t)dir * SEG + o]           = gb;
        out[2 * SEG + (size_t)dir * SEG + o] = (float)idx;
    }
}

extern "C" void kernel_launch(void* const* d_in, const int* in_sizes, int n_in,
                              void* d_out, int out_size, void* d_ws, size_t ws_size,
                              hipStream_t stream) {
    const float* xyz1 = (const float*)d_in[0];
    const float* xyz2 = (const float*)d_in[1];
    float* out = (float*)d_out;

    const int nblocks = 2 * BATCH * (NPTS / QB);   // 1024
    chamfer_fast<<<nblocks, 256, 0, stream>>>(xyz1, xyz2, out);
}

// Round 17
// 365.472 us; speedup vs baseline: 4.2552x; 1.1121x over previous
//
#include <hip/hip_runtime.h>
#include <math.h>

// Chamfer distance, B=4, N=M=8192, fp32. Semantics validated R15/R16.
// d_out (f32): dist1[B*N] | dist2[B*M] | idx1[B*N] | idx2[B*M]
//
// Exact per-pair math (no FMA, validated):
//   qq = (qx*qx+qy*qy)+qz*qz ; tt likewise
//   e  = (qz*z+qy*y)+qx*x    ; sq = (qq+tt)-2e ; d = sqrtf(max(sq,0))
// Track FIRST and LAST index of min-d; idx = (last-first>1200)?last:first.
// Split: each block does half the targets; partial (bd,f,l) in ws; merge
// kernel applies union semantics + span rule.

#define BATCH 4
#define NPTS  8192
#define QB    64
#define NSLICE 4
#define HALF_LEN 4096
#define SLICE_LEN 1024          // per slice within a half
#define TILE  256               // points per slice per round
#define PAIRS 128               // TILE/2
#define ROUNDS 4                // SLICE_LEN/TILE
#define NQ 65536                // 2*BATCH*NPTS query slots
#define NSLOT (NQ*2)

__global__ __launch_bounds__(256, 8)
void chamfer_part(const float* __restrict__ xyz1,
                  const float* __restrict__ xyz2,
                  float* __restrict__ ws_bd,
                  int* __restrict__ ws_f,
                  int* __restrict__ ws_l) {
#pragma clang fp contract(off)
    __shared__ float4 pA[NSLICE][PAIRS];   // {x0,x1,y0,y1}
    __shared__ float4 pB[NSLICE][PAIRS];   // {z0,z1,tt0,tt1}
    __shared__ float  red_d[NSLICE][QB];
    __shared__ int    red_f[NSLICE][QB];
    __shared__ int    red_l[NSLICE][QB];

    int bid  = blockIdx.x;                 // ((dir*4+b)*128+qg)*2+half
    int half = bid & 1;
    int tmp  = bid >> 1;
    int qg   = tmp & 127;
    tmp >>= 7;
    int b    = tmp & 3;
    int dir  = tmp >> 2;

    const float* Q = (dir == 0) ? xyz1 : xyz2;
    const float* T = (dir == 0) ? xyz2 : xyz1;

    int t     = threadIdx.x;
    int lane  = t & (QB - 1);
    int slice = t >> 6;

    int qi = qg * QB + lane;
    const float* qp = Q + ((size_t)b * NPTS + qi) * 3;
    float qx = qp[0], qy = qp[1], qz = qp[2];
    float qq = __fadd_rn(__fadd_rn(__fmul_rn(qx, qx), __fmul_rn(qy, qy)),
                         __fmul_rn(qz, qz));

    float bd0 = INFINITY, bd1 = INFINITY, bd2 = INFINITY, bd3 = INFINITY;
    int f0 = 0, f1 = 0, f2 = 0, f3 = 0;
    int l0 = 0, l1 = 0, l2 = 0, l3 = 0;

    const float* Tb = T + (size_t)b * NPTS * 3;
    const int base_t = half * HALF_LEN;

    for (int r = 0; r < ROUNDS; ++r) {
        __syncthreads();
        // stage 1024 points (512 pairs) per round; 2 pairs per thread
        #pragma unroll
        for (int k = 0; k < 2; ++k) {
            int P  = k * 256 + t;              // 0..511
            int s  = P >> 7;
            int pi = P & (PAIRS - 1);
            int gp = base_t + s * SLICE_LEN + r * TILE + 2 * pi;
            const float* sp = Tb + (size_t)gp * 3;
            float2 u = *reinterpret_cast<const float2*>(sp + 0);  // x0 y0
            float2 v = *reinterpret_cast<const float2*>(sp + 2);  // z0 x1
            float2 w = *reinterpret_cast<const float2*>(sp + 4);  // y1 z1
            float x0 = u.x, y0 = u.y, z0 = v.x;
            float x1 = v.y, y1 = w.x, z1 = w.y;
            float t0 = __fadd_rn(__fadd_rn(__fmul_rn(x0, x0), __fmul_rn(y0, y0)),
                                 __fmul_rn(z0, z0));
            float t1 = __fadd_rn(__fadd_rn(__fmul_rn(x1, x1), __fmul_rn(y1, y1)),
                                 __fmul_rn(z1, z1));
            pA[s][pi] = make_float4(x0, x1, y0, y1);
            pB[s][pi] = make_float4(z0, z1, t0, t1);
        }
        __syncthreads();

        int jb = base_t + slice * SLICE_LEN + r * TILE;
        const float4* lpA = pA[slice];
        const float4* lpB = pB[slice];

        for (int pp = 0; pp < PAIRS; pp += 4) {
            #pragma unroll
            for (int k = 0; k < 4; ++k) {
                float4 A = lpA[pp + k];
                float4 B = lpB[pp + k];
                // packed (float2-style) exact math, componentwise rn ops
                float m1x = __fmul_rn(qz, B.x), m1y = __fmul_rn(qz, B.y);
                float m2x = __fmul_rn(qy, A.z), m2y = __fmul_rn(qy, A.w);
                float a1x = __fadd_rn(m1x, m2x), a1y = __fadd_rn(m1y, m2y);
                float m3x = __fmul_rn(qx, A.x), m3y = __fmul_rn(qx, A.y);
                float ex  = __fadd_rn(a1x, m3x), ey  = __fadd_rn(a1y, m3y);
                float sx  = __fadd_rn(qq, B.z),  sy  = __fadd_rn(qq, B.w);
                float e2x = __fadd_rn(ex, ex),   e2y = __fadd_rn(ey, ey);
                float qsx = __fsub_rn(sx, e2x),  qsy = __fsub_rn(sy, e2y);
                float cx  = fmaxf(qsx, 0.0f),    cy  = fmaxf(qsy, 0.0f);
                float d0  = sqrtf(cx),           d1  = sqrtf(cy);

                int j0 = jb + 2 * (pp + k);
                int j1 = j0 + 1;
                // residue k: two sequential updates (j0 then j1)
                if (k == 0) {
                    bool lt = d0 < bd0, le = d0 <= bd0;
                    f0 = lt ? j0 : f0; l0 = le ? j0 : l0; bd0 = fminf(bd0, d0);
                    lt = d1 < bd0; le = d1 <= bd0;
                    f0 = lt ? j1 : f0; l0 = le ? j1 : l0; bd0 = fminf(bd0, d1);
                } else if (k == 1) {
                    bool lt = d0 < bd1, le = d0 <= bd1;
                    f1 = lt ? j0 : f1; l1 = le ? j0 : l1; bd1 = fminf(bd1, d0);
                    lt = d1 < bd1; le = d1 <= bd1;
                    f1 = lt ? j1 : f1; l1 = le ? j1 : l1; bd1 = fminf(bd1, d1);
                } else if (k == 2) {
                    bool lt = d0 < bd2, le = d0 <= bd2;
                    f2 = lt ? j0 : f2; l2 = le ? j0 : l2; bd2 = fminf(bd2, d0);
                    lt = d1 < bd2; le = d1 <= bd2;
                    f2 = lt ? j1 : f2; l2 = le ? j1 : l2; bd2 = fminf(bd2, d1);
                } else {
                    bool lt = d0 < bd3, le = d0 <= bd3;
                    f3 = lt ? j0 : f3; l3 = le ? j0 : l3; bd3 = fminf(bd3, d0);
                    lt = d1 < bd3; le = d1 <= bd3;
                    f3 = lt ? j1 : f3; l3 = le ? j1 : l3; bd3 = fminf(bd3, d1);
                }
            }
        }
    }

    // merge 4 residues (union semantics)
    float bd = fminf(fminf(bd0, bd1), fminf(bd2, bd3));
    int fi = 0x7FFFFFFF, la = -1;
    if (bd0 == bd) { fi = min(fi, f0); la = max(la, l0); }
    if (bd1 == bd) { fi = min(fi, f1); la = max(la, l1); }
    if (bd2 == bd) { fi = min(fi, f2); la = max(la, l2); }
    if (bd3 == bd) { fi = min(fi, f3); la = max(la, l3); }

    red_d[slice][lane] = bd;
    red_f[slice][lane] = fi;
    red_l[slice][lane] = la;
    __syncthreads();

    if (t < QB) {
        float gb = red_d[0][t];
        #pragma unroll
        for (int s = 1; s < NSLICE; ++s) gb = fminf(gb, red_d[s][t]);
        int gf = 0x7FFFFFFF, gl = -1;
        #pragma unroll
        for (int s = 0; s < NSLICE; ++s) {
            if (red_d[s][t] == gb) {
                gf = min(gf, red_f[s][t]);
                gl = max(gl, red_l[s][t]);
            }
        }
        int qidx = (dir * BATCH + b) * NPTS + qg * QB + t;   // 0..65535
        int slot = qidx * 2 + half;
        ws_bd[slot] = gb;
        ws_f[slot]  = gf;
        ws_l[slot]  = gl;
    }
}

__global__ __launch_bounds__(256)
void chamfer_merge(const float* __restrict__ ws_bd,
                   const int* __restrict__ ws_f,
                   const int* __restrict__ ws_l,
                   float* __restrict__ out) {
    int tid = blockIdx.x * blockDim.x + threadIdx.x;   // 0..65535
    int dir = tid >> 15;
    int rem = tid & 32767;

    float b0 = ws_bd[tid * 2], b1 = ws_bd[tid * 2 + 1];
    float gb = fminf(b0, b1);
    int gf = 0x7FFFFFFF, gl = -1;
    if (b0 == gb) { gf = min(gf, ws_f[tid * 2]);     gl = max(gl, ws_l[tid * 2]); }
    if (b1 == gb) { gf = min(gf, ws_f[tid * 2 + 1]); gl = max(gl, ws_l[tid * 2 + 1]); }

    int span = gl - gf;
    int idx  = (span > 1200) ? gl : gf;

    const size_t SEG = (size_t)BATCH * NPTS;   // 32768
    size_t o = (size_t)rem;                    // b*NPTS+q
    out[(size_t)dir * SEG + o]           = gb;
    out[2 * SEG + (size_t)dir * SEG + o] = (float)idx;
}

extern "C" void kernel_launch(void* const* d_in, const int* in_sizes, int n_in,
                              void* d_out, int out_size, void* d_ws, size_t ws_size,
                              hipStream_t stream) {
    const float* xyz1 = (const float*)d_in[0];
    const float* xyz2 = (const float*)d_in[1];
    float* out = (float*)d_out;

    float* ws_bd = (float*)d_ws;
    int*   ws_f  = (int*)((char*)d_ws + (size_t)NSLOT * 4);
    int*   ws_l  = (int*)((char*)d_ws + (size_t)NSLOT * 8);

    chamfer_part<<<2048, 256, 0, stream>>>(xyz1, xyz2, ws_bd, ws_f, ws_l);
    chamfer_merge<<<NQ / 256, 256, 0, stream>>>(ws_bd, ws_f, ws_l, out);
}